// Round 3
// baseline (890.758 us; speedup 1.0000x reference)
//
#include <hip/hip_runtime.h>

typedef unsigned long long u64;
typedef unsigned int u32;

#define MAXN 8704            // 8700 rounded to 64
#define CHUNK 512            // j-chunk for rank kernel
#define SMAX 6               // buffered far-loads per thread per phase

__device__ inline u64 shfl_xor_u64(u64 v, int m) {
    u32 lo = (u32)v, hi = (u32)(v >> 32);
    lo = (u32)__shfl_xor((int)lo, m, 64);
    hi = (u32)__shfl_xor((int)hi, m, 64);
    return ((u64)hi << 32) | lo;
}

// ---------------- K0: merge + clip + cxcywh->xyxy + sort key + rank init ----
__global__ void prep_kernel(const float* __restrict__ yb, const float* __restrict__ yc,
                            const float* __restrict__ db, const float* __restrict__ dc,
                            int n1, int n,
                            float4* __restrict__ xyxy, float* __restrict__ conf,
                            u32* __restrict__ key, int* __restrict__ rank) {
    int i = blockIdx.x * 256 + threadIdx.x;
    if (i < MAXN) rank[i] = 0;
    if (i >= n) return;
    float cx, cy, w, h, c;
    if (i < n1) {
        const float* b = yb + (size_t)i * 4;
        cx = b[0]; cy = b[1]; w = b[2]; h = b[3]; c = yc[i];
    } else {
        const float* b = db + (size_t)(i - n1) * 4;
        cx = b[0]; cy = b[1]; w = b[2]; h = b[3]; c = dc[i - n1];
    }
    c = fminf(fmaxf(c, 0.0f), 1.0f);
    float hw = w * 0.5f, hh = h * 0.5f;
    xyxy[i] = make_float4(cx - hw, cy - hh, cx + hw, cy + hh);
    conf[i] = c;
    key[i]  = __float_as_uint(c);
}

// ---------------- K1: O(N^2) stable rank ------------------------------------
__global__ void rank_kernel(const u32* __restrict__ key, int n, int* __restrict__ rank) {
    __shared__ __align__(16) u32 sk[CHUNK];
    int t = threadIdx.x;
    int jbase = blockIdx.y * CHUNK;
    for (int s = t; s < CHUNK; s += 256) {
        int j = jbase + s;
        sk[s] = (j < n) ? key[j] : 0u;
    }
    __syncthreads();
    int i = blockIdx.x * 256 + t;
    if (i >= n) return;
    u32 ki = key[i];
    int cnt = 0;
    const uint4* sk4 = (const uint4*)sk;
    for (int s = 0; s < CHUNK / 4; ++s) {
        uint4 k = sk4[s];
        int j = jbase + s * 4;
        cnt += (k.x > ki) || (k.x == ki && (j + 0) < i);
        cnt += (k.y > ki) || (k.y == ki && (j + 1) < i);
        cnt += (k.z > ki) || (k.z == ki && (j + 2) < i);
        cnt += (k.w > ki) || (k.w == ki && (j + 3) < i);
    }
    if (cnt) atomicAdd(&rank[i], cnt);
}

// ---------------- K2: scatter into sorted order -----------------------------
__global__ void scatter_kernel(const float4* __restrict__ xyxy, const float* __restrict__ conf,
                               const int* __restrict__ rank, int n,
                               float4* __restrict__ sbox, float* __restrict__ sconf) {
    int i = blockIdx.x * 256 + threadIdx.x;
    if (i >= n) return;
    int r = rank[i];
    sbox[r]  = xyxy[i];
    sconf[r] = conf[i];
}

// ---------------- K3: suppression bit-matrix (upper triangle) ---------------
// sup[i][bj] bit k set  <=>  j = 64*bj+k, j > i, iou(i,j) > 0.5
__global__ void iou_kernel(const float4* __restrict__ sbox, int n, int nw,
                           u64* __restrict__ sup) {
    int bi = blockIdx.y, bj = blockIdx.x;
    if (bj < bi) return;
    __shared__ float4 cb[64];
    int t  = threadIdx.x;
    int j0 = bj * 64;
    int jt = j0 + t;
    cb[t] = (jt < n) ? sbox[jt] : make_float4(0, 0, 0, 0);
    __syncthreads();
    int i = bi * 64 + t;
    if (i >= n) return;
    float4 a = sbox[i];
    float areaA = (a.z - a.x) * (a.w - a.y);
    u64 word = 0;
    int kmax = min(64, n - j0);
    for (int k = 0; k < kmax; ++k) {
        int j = j0 + k;
        float4 b = cb[k];
        float iw = fmaxf(fminf(a.z, b.z) - fmaxf(a.x, b.x), 0.0f);
        float ih = fmaxf(fminf(a.w, b.w) - fmaxf(a.y, b.y), 0.0f);
        float inter = iw * ih;
        float areaB = (b.z - b.x) * (b.w - b.y);
        float uni = areaA + areaB - inter;
        float iou = inter / fmaxf(uni, 1e-9f);
        if (j > i && iou > 0.5f) word |= (1ULL << k);
    }
    sup[(size_t)i * nw + bj] = word;
}

// ---------------- K4: single-block chunked forward-substitution NMS ---------
// One 512-thread block, all state in LDS. Per 64-row chunk p (one phase, one
// barrier):
//   wave0: ctz-skip serial solve of diag word p (slices in lane regs, fetched
//          via v_readlane -> ~20cy per KEPT row, removed rows skipped free);
//          near-update words p+1..p+3 from speculative band regs (prefetched
//          2 chunks ahead -> no latency on the serial chain); kept-list ->LDS.
//   all:   apply far-load batch issued 2 phases ago (regs long landed, no
//          stall); issue far loads for chunk p-1's kept rows, words >= p+3+1
//          (deadline: word w solved at phase w >= q+4 > q+3 = apply phase).
// Word w coverage: diag (chunk w) + near (chunks w-3..w-1) + far (chunks
// <= w-4). Exact greedy NMS, no global sync, no atomics on global memory.
template<int PW>
__device__ __forceinline__ void phase_step(
    int p, int n, int nw, const u64* __restrict__ sup, int t,
    u64* s_remv, u64* s_kws, u32 (*s_klist)[64], int* s_kcnt, int* s_lg,
    u64& BUj0, u64& BUj1, u64& BUj2, u64& BUj3,
    u64& BIj0, u64& BIj1, u64& BIj2, u64& BIj3,
    u64 (&FV)[SMAX], int (&FT)[SMAX])
{
    constexpr int PR = PW ^ 1;
    // ---- far apply: batch issued 2 phases ago (targets >= p+1, never word p)
    #pragma unroll
    for (int i = 0; i < SMAX; ++i)
        if (FT[i] >= 0) atomicOr(&s_remv[FT[i]], FV[i]);

    if (t < 64) {
        // ---- solve chunk p (wave 0, redundant across 64 lanes) ----
        int rem = n - (p << 6);
        u64 vm = (rem >= 64) ? ~0ull : (rem <= 0 ? 0ull : ((1ull << rem) - 1ull));
        u64 cand = ~s_remv[p] & vm;
        u64 kw = 0;
        u32 dlo = (u32)BUj0, dhi = (u32)(BUj0 >> 32);
        while (cand) {
            int k1 = __builtin_amdgcn_readfirstlane((int)__builtin_ctzll(cand));
            u64 s1 = (((u64)(u32)__builtin_amdgcn_readlane((int)dhi, k1)) << 32)
                   |  ((u64)(u32)__builtin_amdgcn_readlane((int)dlo, k1));
            u64 c1 = cand & ~(1ull << k1);
            kw |= 1ull << k1;
            if (c1) {  // speculative second candidate (suppression is sparse)
                int k2 = __builtin_amdgcn_readfirstlane((int)__builtin_ctzll(c1));
                u64 s2 = (((u64)(u32)__builtin_amdgcn_readlane((int)dhi, k2)) << 32)
                       |  ((u64)(u32)__builtin_amdgcn_readlane((int)dlo, k2));
                if (!((s1 >> k2) & 1ull)) {
                    kw |= 1ull << k2;
                    cand = c1 & ~(1ull << k2) & ~(s1 | s2);
                } else {
                    cand = c1 & ~s1;
                }
            } else cand = 0;
        }
        if (t == 0) s_kws[p] = kw;
        // ---- kept-list for next phase's far-issue (buffer PW) ----
        int kc = __popcll(kw);
        if ((kw >> t) & 1ull)
            s_klist[PW][__popcll(kw & ((1ull << t) - 1ull))] = (u32)t;
        int lg = (kc <= 1) ? 0 : (32 - __builtin_clz(kc - 1));
        int lastl = 63 - __clzll(kw | 1ull);
        if (t >= kc && t < (1 << lg)) s_klist[PW][t] = (u32)lastl;  // pow2 pad (dup-OR ok)
        if (t == 0) { s_kcnt[PW] = kc; s_lg[PW] = lg; }
        // ---- near update: words p+1..p+3 from band regs ----
        u64 mm = ((kw >> t) & 1ull) ? ~0ull : 0ull;
        u64 r1 = BUj1 & mm, r2 = BUj2 & mm, r3 = BUj3 & mm;
        #pragma unroll
        for (int m = 1; m < 64; m <<= 1) {
            r1 |= shfl_xor_u64(r1, m);
            r2 |= shfl_xor_u64(r2, m);
            r3 |= shfl_xor_u64(r3, m);
        }
        if (t == 0) {
            if (p + 1 < nw) atomicOr(&s_remv[p + 1], r1);
            if (p + 2 < nw) atomicOr(&s_remv[p + 2], r2);
            if (p + 3 < nw) atomicOr(&s_remv[p + 3], r3);
        }
        // ---- band prefetch for chunk p+2 (lands with 2-phase slack) ----
        int cc = p + 2;
        size_t rr = (size_t)min(cc * 64 + t, n - 1) * (size_t)nw;
        BIj0 = sup[rr + min(cc,     nw - 1)];
        BIj1 = sup[rr + min(cc + 1, nw - 1)];
        BIj2 = sup[rr + min(cc + 2, nw - 1)];
        BIj3 = sup[rr + min(cc + 3, nw - 1)];
    }
    // ---- far issue for chunk q = p-1 (all 512 threads; reads klist[PR]) ----
    {
        int q = p - 1;
        #pragma unroll
        for (int i = 0; i < SMAX; ++i) FT[i] = -1;
        if (q >= 0) {
            int kc = s_kcnt[PR], lg = s_lg[PR];
            int FW = nw - (q + 4);
            if (kc > 0 && FW > 0) {
                int kp = 1 << lg;
                int pairs = FW << lg;
                #pragma unroll
                for (int i = 0; i < SMAX; ++i) {
                    int idx = t + i * 512;
                    int cidx = min(idx, pairs - 1);
                    int w = (q + 4) + (cidx >> lg);
                    int r = (q << 6) + (int)s_klist[PR][cidx & (kp - 1)];
                    FV[i] = sup[(size_t)r * nw + w];
                    FT[i] = (idx < pairs) ? w : -1;
                }
                // rare overflow path (dense early chunks): apply immediately
                for (int idx = t + SMAX * 512; idx < pairs; idx += 512) {
                    int w = (q + 4) + (idx >> lg);
                    int r = (q << 6) + (int)s_klist[PR][idx & (kp - 1)];
                    atomicOr(&s_remv[w], sup[(size_t)r * nw + w]);
                }
            }
        }
    }
    __syncthreads();
}

__global__ __launch_bounds__(512) void scan_fs(const u64* __restrict__ sup,
                                               const float* __restrict__ sbox,
                                               const float* __restrict__ sconf,
                                               int n, int nw,
                                               float* __restrict__ out) {
    __shared__ u64 s_remv[144];
    __shared__ u64 s_kws[144];
    __shared__ u32 s_klist[2][64];
    __shared__ int s_kcnt[2], s_lg[2];

    int t = threadIdx.x;
    for (int i = t; i < 144; i += 512) { s_remv[i] = 0; s_kws[i] = 0; }
    if (t == 0) { s_kcnt[0] = 0; s_kcnt[1] = 0; s_lg[0] = 0; s_lg[1] = 0; }

    u64 B0j0=0,B0j1=0,B0j2=0,B0j3=0;
    u64 B1j0=0,B1j1=0,B1j2=0,B1j3=0;
    u64 B2j0=0,B2j1=0,B2j2=0,B2j3=0;
    u64 FVA[SMAX], FVB[SMAX]; int FTA[SMAX], FTB[SMAX];
    #pragma unroll
    for (int i = 0; i < SMAX; ++i) { FTA[i] = -1; FTB[i] = -1; FVA[i] = 0; FVB[i] = 0; }

    if (t < 64) {   // prologue: bands for chunks 0 and 1
        size_t r0 = (size_t)t * (size_t)nw;
        B0j0 = sup[r0 + 0]; B0j1 = sup[r0 + 1]; B0j2 = sup[r0 + 2]; B0j3 = sup[r0 + 3];
        size_t r1 = (size_t)(64 + t) * (size_t)nw;
        B1j0 = sup[r1 + 1]; B1j1 = sup[r1 + 2]; B1j2 = sup[r1 + 3]; B1j3 = sup[r1 + 4];
    }
    __syncthreads();

    int NPH = ((nw + 5) / 6) * 6;   // padded tail phases are no-ops (vm=0)
    for (int pb = 0; pb < NPH; pb += 6) {
        phase_step<0>(pb+0, n, nw, sup, t, s_remv, s_kws, s_klist, s_kcnt, s_lg,
                      B0j0,B0j1,B0j2,B0j3, B2j0,B2j1,B2j2,B2j3, FVA, FTA);
        phase_step<1>(pb+1, n, nw, sup, t, s_remv, s_kws, s_klist, s_kcnt, s_lg,
                      B1j0,B1j1,B1j2,B1j3, B0j0,B0j1,B0j2,B0j3, FVB, FTB);
        phase_step<0>(pb+2, n, nw, sup, t, s_remv, s_kws, s_klist, s_kcnt, s_lg,
                      B2j0,B2j1,B2j2,B2j3, B1j0,B1j1,B1j2,B1j3, FVA, FTA);
        phase_step<1>(pb+3, n, nw, sup, t, s_remv, s_kws, s_klist, s_kcnt, s_lg,
                      B0j0,B0j1,B0j2,B0j3, B2j0,B2j1,B2j2,B2j3, FVB, FTB);
        phase_step<0>(pb+4, n, nw, sup, t, s_remv, s_kws, s_klist, s_kcnt, s_lg,
                      B1j0,B1j1,B1j2,B1j3, B0j0,B0j1,B0j2,B0j3, FVA, FTA);
        phase_step<1>(pb+5, n, nw, sup, t, s_remv, s_kws, s_klist, s_kcnt, s_lg,
                      B2j0,B2j1,B2j2,B2j3, B1j0,B1j1,B1j2,B1j3, FVB, FTB);
    }

    // ---- masked output ----
    for (int e = t; e < n * 5; e += 512) {
        int r = e / 5, c5 = e - r * 5;
        float keep = ((s_kws[r >> 6] >> (r & 63)) & 1ull) ? 1.0f : 0.0f;
        float v = (c5 < 4) ? sbox[(size_t)r * 4 + c5] : sconf[r];
        out[e] = v * keep;
    }
}

// ---------------- launch -----------------------------------------------------
extern "C" void kernel_launch(void* const* d_in, const int* in_sizes, int n_in,
                              void* d_out, int out_size, void* d_ws, size_t ws_size,
                              hipStream_t stream) {
    const float* yb = (const float*)d_in[0];
    const float* yc = (const float*)d_in[1];
    const float* db = (const float*)d_in[2];
    const float* dc = (const float*)d_in[3];
    int n1 = in_sizes[1];
    int n2 = in_sizes[3];
    int n  = n1 + n2;                          // 8700
    int nw = (n + 63) / 64;                    // 136

    char* w = (char*)d_ws;
    u64*    sup   = (u64*)w;                                   // MAXN*nw*8 ~ 9.47 MB
    float4* xyxy  = (float4*)(w + (size_t)MAXN * nw * 8);
    float4* sbox  = xyxy + MAXN;
    float*  conf  = (float*)(sbox + MAXN);
    float*  sconf = conf + MAXN;
    u32*    key   = (u32*)(sconf + MAXN);
    int*    rank  = (int*)(key + MAXN);

    int nb = (n + 255) / 256;                                  // 34
    prep_kernel<<<nb, 256, 0, stream>>>(yb, yc, db, dc, n1, n, xyxy, conf, key, rank);

    dim3 g1(nb, (n + CHUNK - 1) / CHUNK);                      // 34 x 17
    rank_kernel<<<g1, 256, 0, stream>>>(key, n, rank);

    scatter_kernel<<<nb, 256, 0, stream>>>(xyxy, conf, rank, n, sbox, sconf);

    dim3 g3(nw, nw);                                           // 136 x 136 (upper tri active)
    iou_kernel<<<g3, 64, 0, stream>>>(sbox, n, nw, sup);

    scan_fs<<<1, 512, 0, stream>>>(sup, (const float*)sbox, sconf, n, nw, (float*)d_out);
}

// Round 4
// 519.049 us; speedup vs baseline: 1.7161x; 1.7161x over previous
//
#include <hip/hip_runtime.h>

typedef unsigned long long u64;
typedef unsigned int u32;

#define MAXN 8704            // 8700 rounded to 64
#define CHUNK 512            // j-chunk for rank kernel

__device__ inline u64 shfl_xor_u64(u64 v, int m) {
    u32 lo = (u32)v, hi = (u32)(v >> 32);
    lo = (u32)__shfl_xor((int)lo, m, 64);
    hi = (u32)__shfl_xor((int)hi, m, 64);
    return ((u64)hi << 32) | lo;
}

// ---------------- K0: merge + clip + cxcywh->xyxy + sort key + rank init ----
__global__ void prep_kernel(const float* __restrict__ yb, const float* __restrict__ yc,
                            const float* __restrict__ db, const float* __restrict__ dc,
                            int n1, int n,
                            float4* __restrict__ xyxy, float* __restrict__ conf,
                            u32* __restrict__ key, int* __restrict__ rank) {
    int i = blockIdx.x * 256 + threadIdx.x;
    if (i < MAXN) rank[i] = 0;
    if (i >= n) return;
    float cx, cy, w, h, c;
    if (i < n1) {
        const float* b = yb + (size_t)i * 4;
        cx = b[0]; cy = b[1]; w = b[2]; h = b[3]; c = yc[i];
    } else {
        const float* b = db + (size_t)(i - n1) * 4;
        cx = b[0]; cy = b[1]; w = b[2]; h = b[3]; c = dc[i - n1];
    }
    c = fminf(fmaxf(c, 0.0f), 1.0f);
    float hw = w * 0.5f, hh = h * 0.5f;
    xyxy[i] = make_float4(cx - hw, cy - hh, cx + hw, cy + hh);
    conf[i] = c;
    key[i]  = __float_as_uint(c);
}

// ---------------- K1: O(N^2) stable rank ------------------------------------
__global__ void rank_kernel(const u32* __restrict__ key, int n, int* __restrict__ rank) {
    __shared__ __align__(16) u32 sk[CHUNK];
    int t = threadIdx.x;
    int jbase = blockIdx.y * CHUNK;
    for (int s = t; s < CHUNK; s += 256) {
        int j = jbase + s;
        sk[s] = (j < n) ? key[j] : 0u;
    }
    __syncthreads();
    int i = blockIdx.x * 256 + t;
    if (i >= n) return;
    u32 ki = key[i];
    int cnt = 0;
    const uint4* sk4 = (const uint4*)sk;
    for (int s = 0; s < CHUNK / 4; ++s) {
        uint4 k = sk4[s];
        int j = jbase + s * 4;
        cnt += (k.x > ki) || (k.x == ki && (j + 0) < i);
        cnt += (k.y > ki) || (k.y == ki && (j + 1) < i);
        cnt += (k.z > ki) || (k.z == ki && (j + 2) < i);
        cnt += (k.w > ki) || (k.w == ki && (j + 3) < i);
    }
    if (cnt) atomicAdd(&rank[i], cnt);
}

// ---------------- K2: scatter into sorted order -----------------------------
__global__ void scatter_kernel(const float4* __restrict__ xyxy, const float* __restrict__ conf,
                               const int* __restrict__ rank, int n,
                               float4* __restrict__ sbox, float* __restrict__ sconf) {
    int i = blockIdx.x * 256 + threadIdx.x;
    if (i >= n) return;
    int r = rank[i];
    sbox[r]  = xyxy[i];
    sconf[r] = conf[i];
}

// ---------------- K3: suppression bit-matrix (upper triangle) ---------------
// sup[i][bj] bit k set  <=>  j = 64*bj+k, j > i, iou(i,j) > 0.5
__global__ void iou_kernel(const float4* __restrict__ sbox, int n, int nw,
                           u64* __restrict__ sup) {
    int bi = blockIdx.y, bj = blockIdx.x;
    if (bj < bi) return;
    __shared__ float4 cb[64];
    int t  = threadIdx.x;
    int j0 = bj * 64;
    int jt = j0 + t;
    cb[t] = (jt < n) ? sbox[jt] : make_float4(0, 0, 0, 0);
    __syncthreads();
    int i = bi * 64 + t;
    if (i >= n) return;
    float4 a = sbox[i];
    float areaA = (a.z - a.x) * (a.w - a.y);
    u64 word = 0;
    int kmax = min(64, n - j0);
    for (int k = 0; k < kmax; ++k) {
        int j = j0 + k;
        float4 b = cb[k];
        float iw = fmaxf(fminf(a.z, b.z) - fmaxf(a.x, b.x), 0.0f);
        float ih = fmaxf(fminf(a.w, b.w) - fmaxf(a.y, b.y), 0.0f);
        float inter = iw * ih;
        float areaB = (b.z - b.x) * (b.w - b.y);
        float uni = areaA + areaB - inter;
        float iou = inter / fmaxf(uni, 1e-9f);
        if (j > i && iou > 0.5f) word |= (1ULL << k);
    }
    sup[(size_t)i * nw + bj] = word;
}

// ---------------- K4: single-block chunked forward-substitution NMS ---------
// One 512-thread block, all state in LDS. Per 64-row chunk p (one barrier):
//   wave0: ctz-skip serial solve of diag word p (slices in lane regs via
//          readlane); near-update words p+1..p+3 from band regs (prefetched
//          2 chunks ahead); kept-list -> LDS (double-buffered).
//   waves 1-7 (396 threads): far-update for chunk q=p-1. Word-owner mapping:
//          group s in {0,1,2} x word-offset wrel; thread ORs column w over
//          rows klist[s], klist[s+3], ... (exact kc bound, clamp-dup = free
//          idempotent OR). Per unroll slot all threads of a group read the
//          SAME row at consecutive words -> coalesced 64B lines. One <=3-way
//          LDS atomicOr per word at the end.
// Word w coverage: diag (chunk w) + near (chunks w-3..w-1, phases w-3..w-1)
// + far (chunks q <= w-4, phases q+1 <= w-3). Exact greedy NMS.
template<int PW>
__device__ __forceinline__ void phase_step(
    int p, int n, int nw, const u64* __restrict__ sup, int t,
    int wrel, int fs, bool isfar,
    u64* s_remv, u64* s_kws, u32 (*s_klist)[64], int* s_kcnt,
    u64& BUj0, u64& BUj1, u64& BUj2, u64& BUj3,
    u64& BIj0, u64& BIj1, u64& BIj2, u64& BIj3)
{
    constexpr int PR = PW ^ 1;
    if (t < 64) {
        // ---- solve chunk p (wave 0, redundant across 64 lanes) ----
        int rem = n - (p << 6);
        u64 vm = (rem >= 64) ? ~0ull : (rem <= 0 ? 0ull : ((1ull << rem) - 1ull));
        u64 cand = ~s_remv[p] & vm;
        u64 kw = 0;
        u32 dlo = (u32)BUj0, dhi = (u32)(BUj0 >> 32);
        while (cand) {
            int k1 = __builtin_amdgcn_readfirstlane((int)__builtin_ctzll(cand));
            u64 s1 = (((u64)(u32)__builtin_amdgcn_readlane((int)dhi, k1)) << 32)
                   |  ((u64)(u32)__builtin_amdgcn_readlane((int)dlo, k1));
            u64 c1 = cand & ~(1ull << k1);
            kw |= 1ull << k1;
            if (c1) {  // speculative second candidate (suppression is sparse)
                int k2 = __builtin_amdgcn_readfirstlane((int)__builtin_ctzll(c1));
                u64 s2 = (((u64)(u32)__builtin_amdgcn_readlane((int)dhi, k2)) << 32)
                       |  ((u64)(u32)__builtin_amdgcn_readlane((int)dlo, k2));
                if (!((s1 >> k2) & 1ull)) {
                    kw |= 1ull << k2;
                    cand = c1 & ~(1ull << k2) & ~(s1 | s2);
                } else {
                    cand = c1 & ~s1;
                }
            } else cand = 0;
        }
        if (t == 0) s_kws[p] = kw;
        // ---- kept-list for next phase's far pass (buffer PW) ----
        if ((kw >> t) & 1ull)
            s_klist[PW][__popcll(kw & ((1ull << t) - 1ull))] = (u32)t;
        if (t == 0) s_kcnt[PW] = __popcll(kw);
        // ---- near update: words p+1..p+3 from band regs ----
        u64 mm = ((kw >> t) & 1ull) ? ~0ull : 0ull;
        u64 r1 = BUj1 & mm, r2 = BUj2 & mm, r3 = BUj3 & mm;
        #pragma unroll
        for (int m = 1; m < 64; m <<= 1) {
            r1 |= shfl_xor_u64(r1, m);
            r2 |= shfl_xor_u64(r2, m);
            r3 |= shfl_xor_u64(r3, m);
        }
        if (t == 0) {
            if (p + 1 < nw) atomicOr((unsigned long long*)&s_remv[p + 1], (unsigned long long)r1);
            if (p + 2 < nw) atomicOr((unsigned long long*)&s_remv[p + 2], (unsigned long long)r2);
            if (p + 3 < nw) atomicOr((unsigned long long*)&s_remv[p + 3], (unsigned long long)r3);
        }
        // ---- band prefetch for chunk p+2 (lands with ~1 phase of slack) ----
        int cc = p + 2;
        size_t rr = (size_t)min(cc * 64 + t, n - 1) * (size_t)nw;
        BIj0 = sup[rr + min(cc,     nw - 1)];
        BIj1 = sup[rr + min(cc + 1, nw - 1)];
        BIj2 = sup[rr + min(cc + 2, nw - 1)];
        BIj3 = sup[rr + min(cc + 3, nw - 1)];
    } else if (isfar && p >= 1) {
        // ---- far update for chunk q = p-1: word-owner columns ----
        int q = p - 1;
        int w = q + 4 + wrel;
        int kc = s_kcnt[PR];
        if (w < nw && fs < kc) {
            const u64* __restrict__ col = sup + (size_t)(q << 6) * nw + w;
            u64 acc = 0;
            for (int base = fs; base < kc; base += 12) {
                int i1 = min(base + 3, kc - 1);
                int i2 = min(base + 6, kc - 1);
                int i3 = min(base + 9, kc - 1);
                u32 r0 = s_klist[PR][base];
                u32 r1 = s_klist[PR][i1];
                u32 r2 = s_klist[PR][i2];
                u32 r3 = s_klist[PR][i3];
                u64 v0 = col[(size_t)r0 * nw];
                u64 v1 = col[(size_t)r1 * nw];
                u64 v2 = col[(size_t)r2 * nw];
                u64 v3 = col[(size_t)r3 * nw];
                acc |= v0 | v1 | v2 | v3;
            }
            if (acc) atomicOr((unsigned long long*)&s_remv[w], (unsigned long long)acc);
        }
    }
    __syncthreads();
}

__global__ __launch_bounds__(512) void scan_fs(const u64* __restrict__ sup,
                                               const float* __restrict__ sbox,
                                               const float* __restrict__ sconf,
                                               int n, int nw,
                                               float* __restrict__ out) {
    __shared__ u64 s_remv[144];
    __shared__ u64 s_kws[144];
    __shared__ u32 s_klist[2][64];
    __shared__ int s_kcnt[2];

    int t = threadIdx.x;
    for (int i = t; i < 144; i += 512) { s_remv[i] = 0; s_kws[i] = 0; }
    if (t == 0) { s_kcnt[0] = 0; s_kcnt[1] = 0; }

    // far mapping (constant per thread): threads 64..459 active
    int tf = t - 64;
    bool isfar = (tf >= 0 && tf < 396);
    int fs   = isfar ? tf / 132 : 0;          // row subset 0..2
    int wrel = isfar ? tf - fs * 132 : 0;     // word offset 0..131

    u64 B0j0=0,B0j1=0,B0j2=0,B0j3=0;
    u64 B1j0=0,B1j1=0,B1j2=0,B1j3=0;
    u64 B2j0=0,B2j1=0,B2j2=0,B2j3=0;

    if (t < 64) {   // prologue: bands for chunks 0 and 1
        size_t r0 = (size_t)t * (size_t)nw;
        B0j0 = sup[r0 + 0]; B0j1 = sup[r0 + 1]; B0j2 = sup[r0 + 2]; B0j3 = sup[r0 + 3];
        size_t r1 = (size_t)(64 + t) * (size_t)nw;
        B1j0 = sup[r1 + 1]; B1j1 = sup[r1 + 2]; B1j2 = sup[r1 + 3]; B1j3 = sup[r1 + 4];
    }
    __syncthreads();

    int NPH = ((nw + 5) / 6) * 6;   // padded tail phases are no-ops (vm=0)
    for (int pb = 0; pb < NPH; pb += 6) {
        phase_step<0>(pb+0, n, nw, sup, t, wrel, fs, isfar, s_remv, s_kws, s_klist, s_kcnt,
                      B0j0,B0j1,B0j2,B0j3, B2j0,B2j1,B2j2,B2j3);
        phase_step<1>(pb+1, n, nw, sup, t, wrel, fs, isfar, s_remv, s_kws, s_klist, s_kcnt,
                      B1j0,B1j1,B1j2,B1j3, B0j0,B0j1,B0j2,B0j3);
        phase_step<0>(pb+2, n, nw, sup, t, wrel, fs, isfar, s_remv, s_kws, s_klist, s_kcnt,
                      B2j0,B2j1,B2j2,B2j3, B1j0,B1j1,B1j2,B1j3);
        phase_step<1>(pb+3, n, nw, sup, t, wrel, fs, isfar, s_remv, s_kws, s_klist, s_kcnt,
                      B0j0,B0j1,B0j2,B0j3, B2j0,B2j1,B2j2,B2j3);
        phase_step<0>(pb+4, n, nw, sup, t, wrel, fs, isfar, s_remv, s_kws, s_klist, s_kcnt,
                      B1j0,B1j1,B1j2,B1j3, B0j0,B0j1,B0j2,B0j3);
        phase_step<1>(pb+5, n, nw, sup, t, wrel, fs, isfar, s_remv, s_kws, s_klist, s_kcnt,
                      B2j0,B2j1,B2j2,B2j3, B1j0,B1j1,B1j2,B1j3);
    }

    // ---- masked output ----
    for (int e = t; e < n * 5; e += 512) {
        int r = e / 5, c5 = e - r * 5;
        float keep = ((s_kws[r >> 6] >> (r & 63)) & 1ull) ? 1.0f : 0.0f;
        float v = (c5 < 4) ? sbox[(size_t)r * 4 + c5] : sconf[r];
        out[e] = v * keep;
    }
}

// ---------------- launch -----------------------------------------------------
extern "C" void kernel_launch(void* const* d_in, const int* in_sizes, int n_in,
                              void* d_out, int out_size, void* d_ws, size_t ws_size,
                              hipStream_t stream) {
    const float* yb = (const float*)d_in[0];
    const float* yc = (const float*)d_in[1];
    const float* db = (const float*)d_in[2];
    const float* dc = (const float*)d_in[3];
    int n1 = in_sizes[1];
    int n2 = in_sizes[3];
    int n  = n1 + n2;                          // 8700
    int nw = (n + 63) / 64;                    // 136

    char* w = (char*)d_ws;
    u64*    sup   = (u64*)w;                                   // MAXN*nw*8 ~ 9.47 MB
    float4* xyxy  = (float4*)(w + (size_t)MAXN * nw * 8);
    float4* sbox  = xyxy + MAXN;
    float*  conf  = (float*)(sbox + MAXN);
    float*  sconf = conf + MAXN;
    u32*    key   = (u32*)(sconf + MAXN);
    int*    rank  = (int*)(key + MAXN);

    int nb = (n + 255) / 256;                                  // 34
    prep_kernel<<<nb, 256, 0, stream>>>(yb, yc, db, dc, n1, n, xyxy, conf, key, rank);

    dim3 g1(nb, (n + CHUNK - 1) / CHUNK);                      // 34 x 17
    rank_kernel<<<g1, 256, 0, stream>>>(key, n, rank);

    scatter_kernel<<<nb, 256, 0, stream>>>(xyxy, conf, rank, n, sbox, sconf);

    dim3 g3(nw, nw);                                           // 136 x 136 (upper tri active)
    iou_kernel<<<g3, 64, 0, stream>>>(sbox, n, nw, sup);

    scan_fs<<<1, 512, 0, stream>>>(sup, (const float*)sbox, sconf, n, nw, (float*)d_out);
}